// Round 1
// baseline (6740.570 us; speedup 1.0000x reference)
//
#include <hip/hip_runtime.h>

#define NN 50000      // nodes per side
#define NE 800000     // edges per side
#define FIN 64        // input features
#define HH 96         // hidden size
#define NG 256        // graphs per batch

// ---------------------------------------------------------------- reductions
__device__ __forceinline__ float wave_sum(float v) {
    #pragma unroll
    for (int off = 32; off > 0; off >>= 1) v += __shfl_down(v, off, 64);
    return v;
}
__device__ __forceinline__ float wave_max(float v) {
    #pragma unroll
    for (int off = 32; off > 0; off >>= 1) v = fmaxf(v, __shfl_down(v, off, 64));
    return v;
}

// ---------------------------------------------------------------- degree / norm
__global__ __launch_bounds__(256) void deg_kernel(const int* __restrict__ dst,
                                                  float* __restrict__ deg) {
    int e = blockIdx.x * 256 + threadIdx.x;
    if (e < NE) atomicAdd(&deg[dst[e]], 1.0f);
}

__global__ __launch_bounds__(256) void dinv_kernel(const float* __restrict__ deg,
                                                   float* __restrict__ dinv) {
    int n = blockIdx.x * 256 + threadIdx.x;
    if (n < NN) dinv[n] = rsqrtf(deg[n] + 1.0f);
}

__global__ __launch_bounds__(256) void norm_kernel(const int* __restrict__ src,
                                                   const int* __restrict__ dst,
                                                   const float* __restrict__ dinv,
                                                   float* __restrict__ norm) {
    int e = blockIdx.x * 256 + threadIdx.x;
    if (e < NE) norm[e] = dinv[src[e]] * dinv[dst[e]];
}

// ---------------------------------------------------------------- graph offsets (batch sorted)
__global__ __launch_bounds__(256) void start_init(int* __restrict__ start) {
    int g = blockIdx.x * 256 + threadIdx.x;
    if (g <= NG) start[g] = NN;
}

__global__ __launch_bounds__(256) void start_scatter(const int* __restrict__ batch,
                                                     int* __restrict__ start) {
    int i = blockIdx.x * 256 + threadIdx.x;
    if (i >= NN) return;
    int b = batch[i];
    int prev = (i == 0) ? -1 : batch[i - 1];
    for (int g = prev + 1; g <= b; ++g) start[g] = i;
}

// ---------------------------------------------------------------- gate MLP (x@gW1 relu @gW2)
__global__ __launch_bounds__(128) void gate_kernel(const float* __restrict__ x,
                                                   const float* __restrict__ gW1,
                                                   const float* __restrict__ gb1,
                                                   const float* __restrict__ gW2,
                                                   const float* __restrict__ gb2,
                                                   float* __restrict__ gate) {
    __shared__ float w1[64 * 64];
    __shared__ float xs[128 * 65];   // +1 pad: bank-conflict-free per-lane rows
    __shared__ float b1[64], w2[64];
    int t = threadIdx.x;
    int base = blockIdx.x * 128;
    for (int idx = t; idx < 64 * 64; idx += 128) w1[idx] = gW1[idx];
    if (t < 64) { b1[t] = gb1[t]; w2[t] = gW2[t]; }
    for (int idx = t; idx < 128 * 64; idx += 128) {
        int n = idx >> 6, k = idx & 63;
        int gn = base + n;
        xs[n * 65 + k] = (gn < NN) ? x[(size_t)gn * 64 + k] : 0.0f;
    }
    __syncthreads();

    float hid[64];
    #pragma unroll
    for (int j = 0; j < 64; ++j) hid[j] = b1[j];
    for (int k = 0; k < 64; ++k) {
        float xv = xs[t * 65 + k];
        #pragma unroll
        for (int j = 0; j < 64; ++j) hid[j] += xv * w1[k * 64 + j];
    }
    float acc = gb2[0];
    #pragma unroll
    for (int j = 0; j < 64; ++j) acc += fmaxf(hid[j], 0.0f) * w2[j];
    int n = base + t;
    if (n < NN) gate[n] = acc;
}

// ---------------------------------------------------------------- node GEMM: out = (relu?)x @ W
// One thread per node; x row in VGPRs; W reads are wave-uniform (scalar loads).
template <int K, bool RELU>
__global__ __launch_bounds__(256) void node_gemm(const float* __restrict__ x,
                                                 const float* __restrict__ W,
                                                 float* __restrict__ out) {
    int n = blockIdx.x * 256 + threadIdx.x;
    if (n >= NN) return;
    float xr[K];
    #pragma unroll
    for (int k4 = 0; k4 < K; k4 += 4) {
        float4 v = *reinterpret_cast<const float4*>(x + (size_t)n * K + k4);
        if (RELU) {
            v.x = fmaxf(v.x, 0.0f); v.y = fmaxf(v.y, 0.0f);
            v.z = fmaxf(v.z, 0.0f); v.w = fmaxf(v.w, 0.0f);
        }
        xr[k4] = v.x; xr[k4 + 1] = v.y; xr[k4 + 2] = v.z; xr[k4 + 3] = v.w;
    }
    for (int c = 0; c < HH; c += 4) {
        float a0 = 0.f, a1 = 0.f, a2 = 0.f, a3 = 0.f;
        #pragma unroll
        for (int k = 0; k < K; ++k) {
            float4 w = *reinterpret_cast<const float4*>(W + k * HH + c);  // uniform
            a0 += xr[k] * w.x; a1 += xr[k] * w.y;
            a2 += xr[k] * w.z; a3 += xr[k] * w.w;
        }
        float4 r; r.x = a0; r.y = a1; r.z = a2; r.w = a3;
        *reinterpret_cast<float4*>(out + (size_t)n * HH + c) = r;
    }
}

// ---------------------------------------------------------------- agg = dinv^2 * xw + bias
__global__ __launch_bounds__(256) void agg_init(const float* __restrict__ xw,
                                                const float* __restrict__ dinv,
                                                const float* __restrict__ bias,
                                                float* __restrict__ agg) {
    int i = blockIdx.x * 256 + threadIdx.x;   // over NN*24 float4s
    if (i >= NN * 24) return;
    int n = i / 24, q = i % 24;
    float d = dinv[n];
    float d2 = d * d;
    float4 v = reinterpret_cast<const float4*>(xw)[i];
    float4 b = reinterpret_cast<const float4*>(bias)[q];
    float4 r;
    r.x = d2 * v.x + b.x; r.y = d2 * v.y + b.y;
    r.z = d2 * v.z + b.z; r.w = d2 * v.w + b.w;
    reinterpret_cast<float4*>(agg)[i] = r;
}

// ---------------------------------------------------------------- edge scatter: agg[dst] += norm*xw[src]
__global__ __launch_bounds__(256) void edge_scatter(const float* __restrict__ xw,
                                                    const float* __restrict__ norm,
                                                    const int* __restrict__ src,
                                                    const int* __restrict__ dst,
                                                    float* __restrict__ agg) {
    int i = blockIdx.x * 256 + threadIdx.x;   // over NE*24 float4s
    if (i >= NE * 24) return;
    int e = i / 24, q = i % 24;
    int s = src[e], d = dst[e];
    float nr = norm[e];
    float4 v = reinterpret_cast<const float4*>(xw)[s * 24 + q];
    float* out = agg + (size_t)d * HH + q * 4;
    atomicAdd(out + 0, nr * v.x);
    atomicAdd(out + 1, nr * v.y);
    atomicAdd(out + 2, nr * v.z);
    atomicAdd(out + 3, nr * v.w);
}

// ---------------------------------------------------------------- per-graph pooling (att + mean)
__global__ __launch_bounds__(256) void pool_kernel(const float* __restrict__ gate,
                                                   const float* __restrict__ x,
                                                   const float* __restrict__ h,
                                                   const int* __restrict__ start,
                                                   float* __restrict__ attOut,
                                                   float* __restrict__ meanOut) {
    int g = blockIdx.x;
    int s = start[g], e = start[g + 1];
    int t = threadIdx.x;
    int cnt = e - s;
    __shared__ float red[4];
    __shared__ float s_m, s_den;

    // phase A: max gate
    float lm = -3.0e38f;
    for (int i = s + t; i < e; i += 256) lm = fmaxf(lm, gate[i]);
    lm = wave_max(lm);
    if ((t & 63) == 0) red[t >> 6] = lm;
    __syncthreads();
    if (t == 0) s_m = fmaxf(fmaxf(red[0], red[1]), fmaxf(red[2], red[3]));
    __syncthreads();
    float m = s_m;

    // phase B: denom
    float ls = 0.0f;
    for (int i = s + t; i < e; i += 256) ls += expf(gate[i] - m);
    ls = wave_sum(ls);
    __syncthreads();
    if ((t & 63) == 0) red[t >> 6] = ls;
    __syncthreads();
    if (t == 0) s_den = red[0] + red[1] + red[2] + red[3];
    __syncthreads();
    float den = s_den;

    // phase C: weighted feature sums (lanes 0..63: att over x; 64..159: mean over h)
    if (t < 160) {
        float acc = 0.0f;
        if (t < 64) {
            for (int i = s; i < e; ++i) acc += expf(gate[i] - m) * x[(size_t)i * FIN + t];
            attOut[g * FIN + t] = (cnt > 0) ? acc / den : 0.0f;
        } else {
            int c = t - 64;
            for (int i = s; i < e; ++i) acc += h[(size_t)i * HH + c];
            meanOut[g * HH + c] = acc / fmaxf((float)cnt, 1.0f);
        }
    }
}

// ---------------------------------------------------------------- final MLP
__global__ __launch_bounds__(128) void final_mlp(const float* __restrict__ meanP,
                                                 const float* __restrict__ meanD,
                                                 const float* __restrict__ attP,
                                                 const float* __restrict__ attD,
                                                 const float* __restrict__ lW0,
                                                 const float* __restrict__ lb0,
                                                 const float* __restrict__ lW1,
                                                 const float* __restrict__ lb1,
                                                 float* __restrict__ out) {
    __shared__ float in[2 * HH + 2 * FIN];   // 320
    __shared__ float red[2];
    int g = blockIdx.x, t = threadIdx.x;
    for (int idx = t; idx < 320; idx += 128) {
        float v;
        if (idx < 96)       v = meanP[g * HH + idx];
        else if (idx < 192) v = meanD[g * HH + idx - 96];
        else if (idx < 256) v = attP[g * FIN + idx - 192];
        else                v = attD[g * FIN + idx - 256];
        in[idx] = v;
    }
    __syncthreads();
    float hidv = 0.0f;
    if (t < HH) {
        float acc = lb0[t];
        for (int k = 0; k < 320; ++k) acc += in[k] * lW0[k * HH + t];
        hidv = fmaxf(acc, 0.0f) * lW1[t];
    }
    float v = wave_sum(hidv);
    if ((t & 63) == 0) red[t >> 6] = v;
    __syncthreads();
    if (t == 0) out[g] = red[0] + red[1] + lb1[0];
}

// ---------------------------------------------------------------- launch
extern "C" void kernel_launch(void* const* d_in, const int* in_sizes, int n_in,
                              void* d_out, int out_size, void* d_ws, size_t ws_size,
                              hipStream_t stream) {
    const float* x_p = (const float*)d_in[0];
    const float* x_d = (const float*)d_in[1];
    const int* ei_p = (const int*)d_in[4];
    const int* ei_d = (const int*)d_in[5];
    const int* batch_p = (const int*)d_in[6];
    const int* batch_d = (const int*)d_in[7];
    const float* Wp0 = (const float*)d_in[8];  const float* bp0 = (const float*)d_in[9];
    const float* Wp1 = (const float*)d_in[10]; const float* bp1 = (const float*)d_in[11];
    const float* Wp2 = (const float*)d_in[12]; const float* bp2 = (const float*)d_in[13];
    const float* Wd0 = (const float*)d_in[14]; const float* bd0 = (const float*)d_in[15];
    const float* Wd1 = (const float*)d_in[16]; const float* bd1 = (const float*)d_in[17];
    const float* Wd2 = (const float*)d_in[18]; const float* bd2 = (const float*)d_in[19];
    const float* gW1 = (const float*)d_in[20]; const float* gb1 = (const float*)d_in[21];
    const float* gW2 = (const float*)d_in[22]; const float* gb2 = (const float*)d_in[23];
    const float* lW0 = (const float*)d_in[24]; const float* lb0 = (const float*)d_in[25];
    const float* lW1 = (const float*)d_in[26]; const float* lb1 = (const float*)d_in[27];

    const int* src_p = ei_p;        const int* dst_p = ei_p + NE;
    const int* src_d = ei_d;        const int* dst_d = ei_d + NE;

    // -------- workspace carve-up
    char* ws = (char*)d_ws;
    size_t off = 0;
    auto alloc = [&](size_t bytes) -> void* {
        void* p = ws + off;
        off = (off + bytes + 255) & ~(size_t)255;
        return p;
    };
    float* bufA = (float*)alloc((size_t)NN * HH * 4);
    float* bufB = (float*)alloc((size_t)NN * HH * 4);
    float* bufC = (float*)alloc((size_t)NN * HH * 4);   // xw scratch
    float* deg_p = (float*)alloc(NN * 4);
    float* deg_d = (float*)alloc(NN * 4);
    float* dinv_p = (float*)alloc(NN * 4);
    float* dinv_d = (float*)alloc(NN * 4);
    float* norm_p = (float*)alloc(NE * 4);
    float* norm_d = (float*)alloc(NE * 4);
    float* gate_p = (float*)alloc(NN * 4);
    float* gate_d = (float*)alloc(NN * 4);
    int* start_p = (int*)alloc((NG + 1) * 4);
    int* start_d = (int*)alloc((NG + 1) * 4);
    float* meanP = (float*)alloc(NG * HH * 4);
    float* meanD = (float*)alloc(NG * HH * 4);
    float* attP  = (float*)alloc(NG * FIN * 4);
    float* attD  = (float*)alloc(NG * FIN * 4);
    (void)ws_size; (void)n_in; (void)in_sizes; (void)out_size;

    const int BE = (NE + 255) / 256;
    const int BN = (NN + 255) / 256;
    const int BEV = (NE * 24 + 255) / 256;
    const int BNV = (NN * 24 + 255) / 256;

    // -------- degree / norm / offsets / gate
    hipMemsetAsync(deg_p, 0, NN * 4, stream);
    hipMemsetAsync(deg_d, 0, NN * 4, stream);
    deg_kernel<<<BE, 256, 0, stream>>>(dst_p, deg_p);
    deg_kernel<<<BE, 256, 0, stream>>>(dst_d, deg_d);
    dinv_kernel<<<BN, 256, 0, stream>>>(deg_p, dinv_p);
    dinv_kernel<<<BN, 256, 0, stream>>>(deg_d, dinv_d);
    norm_kernel<<<BE, 256, 0, stream>>>(src_p, dst_p, dinv_p, norm_p);
    norm_kernel<<<BE, 256, 0, stream>>>(src_d, dst_d, dinv_d, norm_d);
    start_init<<<2, 256, 0, stream>>>(start_p);
    start_init<<<2, 256, 0, stream>>>(start_d);
    start_scatter<<<BN, 256, 0, stream>>>(batch_p, start_p);
    start_scatter<<<BN, 256, 0, stream>>>(batch_d, start_d);
    gate_kernel<<<(NN + 127) / 128, 128, 0, stream>>>(x_p, gW1, gb1, gW2, gb2, gate_p);
    gate_kernel<<<(NN + 127) / 128, 128, 0, stream>>>(x_d, gW1, gb1, gW2, gb2, gate_d);

    // -------- side p: 3 GCN layers
    node_gemm<FIN, false><<<BN, 256, 0, stream>>>(x_p, Wp0, bufC);
    agg_init<<<BNV, 256, 0, stream>>>(bufC, dinv_p, bp0, bufA);
    edge_scatter<<<BEV, 256, 0, stream>>>(bufC, norm_p, src_p, dst_p, bufA);
    node_gemm<HH, true><<<BN, 256, 0, stream>>>(bufA, Wp1, bufC);
    agg_init<<<BNV, 256, 0, stream>>>(bufC, dinv_p, bp1, bufB);
    edge_scatter<<<BEV, 256, 0, stream>>>(bufC, norm_p, src_p, dst_p, bufB);
    node_gemm<HH, true><<<BN, 256, 0, stream>>>(bufB, Wp2, bufC);
    agg_init<<<BNV, 256, 0, stream>>>(bufC, dinv_p, bp2, bufA);
    edge_scatter<<<BEV, 256, 0, stream>>>(bufC, norm_p, src_p, dst_p, bufA);
    pool_kernel<<<NG, 256, 0, stream>>>(gate_p, x_p, bufA, start_p, attP, meanP);

    // -------- side d: 3 GCN layers
    node_gemm<FIN, false><<<BN, 256, 0, stream>>>(x_d, Wd0, bufC);
    agg_init<<<BNV, 256, 0, stream>>>(bufC, dinv_d, bd0, bufA);
    edge_scatter<<<BEV, 256, 0, stream>>>(bufC, norm_d, src_d, dst_d, bufA);
    node_gemm<HH, true><<<BN, 256, 0, stream>>>(bufA, Wd1, bufC);
    agg_init<<<BNV, 256, 0, stream>>>(bufC, dinv_d, bd1, bufB);
    edge_scatter<<<BEV, 256, 0, stream>>>(bufC, norm_d, src_d, dst_d, bufB);
    node_gemm<HH, true><<<BN, 256, 0, stream>>>(bufB, Wd2, bufC);
    agg_init<<<BNV, 256, 0, stream>>>(bufC, dinv_d, bd2, bufA);
    edge_scatter<<<BEV, 256, 0, stream>>>(bufC, norm_d, src_d, dst_d, bufA);
    pool_kernel<<<NG, 256, 0, stream>>>(gate_d, x_d, bufA, start_d, attD, meanD);

    // -------- final MLP
    final_mlp<<<NG, 128, 0, stream>>>(meanP, meanD, attP, attD,
                                      lW0, lb0, lW1, lb1, (float*)d_out);
}

// Round 2
// 1129.916 us; speedup vs baseline: 5.9656x; 5.9656x over previous
//
#include <hip/hip_runtime.h>

#define NN 50000      // nodes per side
#define NE 800000     // edges per side
#define FIN 64        // input features
#define HH 96        // hidden size
#define NG 256        // graphs per batch
#define NB ((NN + 255) / 256)   // scan blocks

// ---------------------------------------------------------------- reductions
__device__ __forceinline__ float wave_sum(float v) {
    #pragma unroll
    for (int off = 32; off > 0; off >>= 1) v += __shfl_down(v, off, 64);
    return v;
}
__device__ __forceinline__ float wave_max(float v) {
    #pragma unroll
    for (int off = 32; off > 0; off >>= 1) v = fmaxf(v, __shfl_down(v, off, 64));
    return v;
}

// ---------------------------------------------------------------- degree count (int)
__global__ __launch_bounds__(256) void count_kernel(const int* __restrict__ dst,
                                                    int* __restrict__ cnt) {
    int e = blockIdx.x * 256 + threadIdx.x;
    if (e < NE) atomicAdd(&cnt[dst[e]], 1);
}

__global__ __launch_bounds__(256) void dinv_kernel(const int* __restrict__ cnt,
                                                   float* __restrict__ dinv) {
    int n = blockIdx.x * 256 + threadIdx.x;
    if (n < NN) dinv[n] = rsqrtf((float)cnt[n] + 1.0f);
}

// ---------------------------------------------------------------- exclusive scan (3 kernels)
__global__ __launch_bounds__(256) void scan1(const int* __restrict__ cnt,
                                             int* __restrict__ blocksum) {
    __shared__ int s[256];
    int t = threadIdx.x, i = blockIdx.x * 256 + t;
    s[t] = (i < NN) ? cnt[i] : 0;
    __syncthreads();
    for (int off = 128; off > 0; off >>= 1) {
        if (t < off) s[t] += s[t + off];
        __syncthreads();
    }
    if (t == 0) blocksum[blockIdx.x] = s[0];
}

__global__ __launch_bounds__(256) void scan2(int* __restrict__ blocksum,
                                             int* __restrict__ blockoff) {
    if (threadIdx.x == 0) {
        int acc = 0;
        for (int b = 0; b < NB; ++b) { blockoff[b] = acc; acc += blocksum[b]; }
    }
}

__global__ __launch_bounds__(256) void scan3(const int* __restrict__ cnt,
                                             const int* __restrict__ blockoff,
                                             int* __restrict__ rowptr,
                                             int* __restrict__ cursor) {
    __shared__ int s[256];
    int t = threadIdx.x, i = blockIdx.x * 256 + t;
    int c = (i < NN) ? cnt[i] : 0;
    s[t] = c;
    __syncthreads();
    for (int off = 1; off < 256; off <<= 1) {
        int v = (t >= off) ? s[t - off] : 0;
        __syncthreads();
        s[t] += v;
        __syncthreads();
    }
    int excl = s[t] - c + blockoff[blockIdx.x];
    if (i < NN) { rowptr[i] = excl; cursor[i] = excl; }
    if (i == NN - 1) rowptr[NN] = excl + c;   // == NE
}

// ---------------------------------------------------------------- edge permute into CSR
__global__ __launch_bounds__(256) void permute_kernel(const int* __restrict__ src,
                                                      const int* __restrict__ dst,
                                                      const float* __restrict__ dinv,
                                                      int* __restrict__ cursor,
                                                      int* __restrict__ eSrc,
                                                      float* __restrict__ eNorm) {
    int e = blockIdx.x * 256 + threadIdx.x;
    if (e >= NE) return;
    int s = src[e], d = dst[e];
    int pos = atomicAdd(&cursor[d], 1);
    eSrc[pos] = s;
    eNorm[pos] = dinv[s] * dinv[d];
}

// ---------------------------------------------------------------- graph offsets (batch sorted)
__global__ __launch_bounds__(256) void start_init(int* __restrict__ start) {
    int g = blockIdx.x * 256 + threadIdx.x;
    if (g <= NG) start[g] = NN;
}

__global__ __launch_bounds__(256) void start_scatter(const int* __restrict__ batch,
                                                     int* __restrict__ start) {
    int i = blockIdx.x * 256 + threadIdx.x;
    if (i >= NN) return;
    int b = batch[i];
    int prev = (i == 0) ? -1 : batch[i - 1];
    for (int g = prev + 1; g <= b; ++g) start[g] = i;
}

// ---------------------------------------------------------------- gate MLP (x@gW1 relu @gW2)
__global__ __launch_bounds__(128) void gate_kernel(const float* __restrict__ x,
                                                   const float* __restrict__ gW1,
                                                   const float* __restrict__ gb1,
                                                   const float* __restrict__ gW2,
                                                   const float* __restrict__ gb2,
                                                   float* __restrict__ gate) {
    __shared__ float w1[64 * 64];
    __shared__ float xs[128 * 65];
    __shared__ float b1[64], w2[64];
    int t = threadIdx.x;
    int base = blockIdx.x * 128;
    for (int idx = t; idx < 64 * 64; idx += 128) w1[idx] = gW1[idx];
    if (t < 64) { b1[t] = gb1[t]; w2[t] = gW2[t]; }
    for (int idx = t; idx < 128 * 64; idx += 128) {
        int n = idx >> 6, k = idx & 63;
        int gn = base + n;
        xs[n * 65 + k] = (gn < NN) ? x[(size_t)gn * 64 + k] : 0.0f;
    }
    __syncthreads();

    float hid[64];
    #pragma unroll
    for (int j = 0; j < 64; ++j) hid[j] = b1[j];
    for (int k = 0; k < 64; ++k) {
        float xv = xs[t * 65 + k];
        #pragma unroll
        for (int j = 0; j < 64; ++j) hid[j] += xv * w1[k * 64 + j];
    }
    float acc = gb2[0];
    #pragma unroll
    for (int j = 0; j < 64; ++j) acc += fmaxf(hid[j], 0.0f) * w2[j];
    int n = base + t;
    if (n < NN) gate[n] = acc;
}

// ---------------------------------------------------------------- node GEMM: out = (relu?)x @ W
template <int K, bool RELU>
__global__ __launch_bounds__(256) void node_gemm(const float* __restrict__ x,
                                                 const float* __restrict__ W,
                                                 float* __restrict__ out) {
    int n = blockIdx.x * 256 + threadIdx.x;
    if (n >= NN) return;
    float xr[K];
    #pragma unroll
    for (int k4 = 0; k4 < K; k4 += 4) {
        float4 v = *reinterpret_cast<const float4*>(x + (size_t)n * K + k4);
        if (RELU) {
            v.x = fmaxf(v.x, 0.0f); v.y = fmaxf(v.y, 0.0f);
            v.z = fmaxf(v.z, 0.0f); v.w = fmaxf(v.w, 0.0f);
        }
        xr[k4] = v.x; xr[k4 + 1] = v.y; xr[k4 + 2] = v.z; xr[k4 + 3] = v.w;
    }
    for (int c = 0; c < HH; c += 4) {
        float a0 = 0.f, a1 = 0.f, a2 = 0.f, a3 = 0.f;
        #pragma unroll
        for (int k = 0; k < K; ++k) {
            float4 w = *reinterpret_cast<const float4*>(W + k * HH + c);  // uniform
            a0 += xr[k] * w.x; a1 += xr[k] * w.y;
            a2 += xr[k] * w.z; a3 += xr[k] * w.w;
        }
        float4 r; r.x = a0; r.y = a1; r.z = a2; r.w = a3;
        *reinterpret_cast<float4*>(out + (size_t)n * HH + c) = r;
    }
}

// ---------------------------------------------------------------- CSR gather:
// out[n] = dinv[n]^2 * xw[n] + bias + sum_{e in row(n)} norm_e * xw[src_e]
__global__ __launch_bounds__(256) void gather_kernel(const float* __restrict__ xw,
                                                     const float* __restrict__ dinv,
                                                     const float* __restrict__ bias,
                                                     const int* __restrict__ rowptr,
                                                     const int* __restrict__ eSrc,
                                                     const float* __restrict__ eNorm,
                                                     float* __restrict__ out) {
    int i = blockIdx.x * 256 + threadIdx.x;   // over NN*24 float4s
    if (i >= NN * 24) return;
    int n = i / 24, q = i % 24;
    float d = dinv[n];
    float d2 = d * d;
    float4 v = reinterpret_cast<const float4*>(xw)[i];
    float4 b = reinterpret_cast<const float4*>(bias)[q];
    float ax = d2 * v.x + b.x, ay = d2 * v.y + b.y;
    float az = d2 * v.z + b.z, aw = d2 * v.w + b.w;
    int r0 = rowptr[n], r1 = rowptr[n + 1];
    for (int r = r0; r < r1; ++r) {
        int s = eSrc[r];          // wave-uniform within a node's lane group
        float nr = eNorm[r];
        float4 u = reinterpret_cast<const float4*>(xw)[s * 24 + q];
        ax += nr * u.x; ay += nr * u.y;
        az += nr * u.z; aw += nr * u.w;
    }
    float4 r; r.x = ax; r.y = ay; r.z = az; r.w = aw;
    reinterpret_cast<float4*>(out)[i] = r;
}

// ---------------------------------------------------------------- per-graph pooling (att + mean)
__global__ __launch_bounds__(256) void pool_kernel(const float* __restrict__ gate,
                                                   const float* __restrict__ x,
                                                   const float* __restrict__ h,
                                                   const int* __restrict__ start,
                                                   float* __restrict__ attOut,
                                                   float* __restrict__ meanOut) {
    int g = blockIdx.x;
    int s = start[g], e = start[g + 1];
    int t = threadIdx.x;
    int cnt = e - s;
    __shared__ float red[4];
    __shared__ float s_m, s_den;

    float lm = -3.0e38f;
    for (int i = s + t; i < e; i += 256) lm = fmaxf(lm, gate[i]);
    lm = wave_max(lm);
    if ((t & 63) == 0) red[t >> 6] = lm;
    __syncthreads();
    if (t == 0) s_m = fmaxf(fmaxf(red[0], red[1]), fmaxf(red[2], red[3]));
    __syncthreads();
    float m = s_m;

    float ls = 0.0f;
    for (int i = s + t; i < e; i += 256) ls += expf(gate[i] - m);
    ls = wave_sum(ls);
    __syncthreads();
    if ((t & 63) == 0) red[t >> 6] = ls;
    __syncthreads();
    if (t == 0) s_den = red[0] + red[1] + red[2] + red[3];
    __syncthreads();
    float den = s_den;

    if (t < 160) {
        float acc = 0.0f;
        if (t < 64) {
            for (int i = s; i < e; ++i) acc += expf(gate[i] - m) * x[(size_t)i * FIN + t];
            attOut[g * FIN + t] = (cnt > 0) ? acc / den : 0.0f;
        } else {
            int c = t - 64;
            for (int i = s; i < e; ++i) acc += h[(size_t)i * HH + c];
            meanOut[g * HH + c] = acc / fmaxf((float)cnt, 1.0f);
        }
    }
}

// ---------------------------------------------------------------- final MLP
__global__ __launch_bounds__(128) void final_mlp(const float* __restrict__ meanP,
                                                 const float* __restrict__ meanD,
                                                 const float* __restrict__ attP,
                                                 const float* __restrict__ attD,
                                                 const float* __restrict__ lW0,
                                                 const float* __restrict__ lb0,
                                                 const float* __restrict__ lW1,
                                                 const float* __restrict__ lb1,
                                                 float* __restrict__ out) {
    __shared__ float in[2 * HH + 2 * FIN];   // 320
    __shared__ float red[2];
    int g = blockIdx.x, t = threadIdx.x;
    for (int idx = t; idx < 320; idx += 128) {
        float v;
        if (idx < 96)       v = meanP[g * HH + idx];
        else if (idx < 192) v = meanD[g * HH + idx - 96];
        else if (idx < 256) v = attP[g * FIN + idx - 192];
        else                v = attD[g * FIN + idx - 256];
        in[idx] = v;
    }
    __syncthreads();
    float hidv = 0.0f;
    if (t < HH) {
        float acc = lb0[t];
        for (int k = 0; k < 320; ++k) acc += in[k] * lW0[k * HH + t];
        hidv = fmaxf(acc, 0.0f) * lW1[t];
    }
    float v = wave_sum(hidv);
    if ((t & 63) == 0) red[t >> 6] = v;
    __syncthreads();
    if (t == 0) out[g] = red[0] + red[1] + lb1[0];
}

// ---------------------------------------------------------------- launch
extern "C" void kernel_launch(void* const* d_in, const int* in_sizes, int n_in,
                              void* d_out, int out_size, void* d_ws, size_t ws_size,
                              hipStream_t stream) {
    const float* x_p = (const float*)d_in[0];
    const float* x_d = (const float*)d_in[1];
    const int* ei_p = (const int*)d_in[4];
    const int* ei_d = (const int*)d_in[5];
    const int* batch_p = (const int*)d_in[6];
    const int* batch_d = (const int*)d_in[7];
    const float* Wp0 = (const float*)d_in[8];  const float* bp0 = (const float*)d_in[9];
    const float* Wp1 = (const float*)d_in[10]; const float* bp1 = (const float*)d_in[11];
    const float* Wp2 = (const float*)d_in[12]; const float* bp2 = (const float*)d_in[13];
    const float* Wd0 = (const float*)d_in[14]; const float* bd0 = (const float*)d_in[15];
    const float* Wd1 = (const float*)d_in[16]; const float* bd1 = (const float*)d_in[17];
    const float* Wd2 = (const float*)d_in[18]; const float* bd2 = (const float*)d_in[19];
    const float* gW1 = (const float*)d_in[20]; const float* gb1 = (const float*)d_in[21];
    const float* gW2 = (const float*)d_in[22]; const float* gb2 = (const float*)d_in[23];
    const float* lW0 = (const float*)d_in[24]; const float* lb0 = (const float*)d_in[25];
    const float* lW1 = (const float*)d_in[26]; const float* lb1 = (const float*)d_in[27];

    const int* src_p = ei_p;        const int* dst_p = ei_p + NE;
    const int* src_d = ei_d;        const int* dst_d = ei_d + NE;

    // -------- workspace carve-up
    char* ws = (char*)d_ws;
    size_t off = 0;
    auto alloc = [&](size_t bytes) -> void* {
        void* p = ws + off;
        off = (off + bytes + 255) & ~(size_t)255;
        return p;
    };
    float* bufA = (float*)alloc((size_t)NN * HH * 4);
    float* bufB = (float*)alloc((size_t)NN * HH * 4);
    float* bufC = (float*)alloc((size_t)NN * HH * 4);   // xw scratch
    int* cnt_p = (int*)alloc(NN * 4);
    int* cnt_d = (int*)alloc(NN * 4);
    float* dinv_p = (float*)alloc(NN * 4);
    float* dinv_d = (float*)alloc(NN * 4);
    int* rowptr_p = (int*)alloc((NN + 1) * 4);
    int* rowptr_d = (int*)alloc((NN + 1) * 4);
    int* cursor_p = (int*)alloc(NN * 4);
    int* cursor_d = (int*)alloc(NN * 4);
    int* eSrc_p = (int*)alloc((size_t)NE * 4);
    int* eSrc_d = (int*)alloc((size_t)NE * 4);
    float* eNorm_p = (float*)alloc((size_t)NE * 4);
    float* eNorm_d = (float*)alloc((size_t)NE * 4);
    int* blocksum = (int*)alloc(NB * 4);
    int* blockoff = (int*)alloc(NB * 4);
    float* gate_p = (float*)alloc(NN * 4);
    float* gate_d = (float*)alloc(NN * 4);
    int* start_p = (int*)alloc((NG + 1) * 4);
    int* start_d = (int*)alloc((NG + 1) * 4);
    float* meanP = (float*)alloc(NG * HH * 4);
    float* meanD = (float*)alloc(NG * HH * 4);
    float* attP  = (float*)alloc(NG * FIN * 4);
    float* attD  = (float*)alloc(NG * FIN * 4);
    (void)ws_size; (void)n_in; (void)in_sizes; (void)out_size;

    const int BE = (NE + 255) / 256;
    const int BN = NB;
    const int BNV = (NN * 24 + 255) / 256;

    // -------- CSR build, side p then d (plus offsets / gate)
    hipMemsetAsync(cnt_p, 0, NN * 4, stream);
    hipMemsetAsync(cnt_d, 0, NN * 4, stream);
    count_kernel<<<BE, 256, 0, stream>>>(dst_p, cnt_p);
    count_kernel<<<BE, 256, 0, stream>>>(dst_d, cnt_d);
    dinv_kernel<<<BN, 256, 0, stream>>>(cnt_p, dinv_p);
    dinv_kernel<<<BN, 256, 0, stream>>>(cnt_d, dinv_d);
    scan1<<<NB, 256, 0, stream>>>(cnt_p, blocksum);
    scan2<<<1, 256, 0, stream>>>(blocksum, blockoff);
    scan3<<<NB, 256, 0, stream>>>(cnt_p, blockoff, rowptr_p, cursor_p);
    scan1<<<NB, 256, 0, stream>>>(cnt_d, blocksum);
    scan2<<<1, 256, 0, stream>>>(blocksum, blockoff);
    scan3<<<NB, 256, 0, stream>>>(cnt_d, blockoff, rowptr_d, cursor_d);
    permute_kernel<<<BE, 256, 0, stream>>>(src_p, dst_p, dinv_p, cursor_p, eSrc_p, eNorm_p);
    permute_kernel<<<BE, 256, 0, stream>>>(src_d, dst_d, dinv_d, cursor_d, eSrc_d, eNorm_d);
    start_init<<<2, 256, 0, stream>>>(start_p);
    start_init<<<2, 256, 0, stream>>>(start_d);
    start_scatter<<<BN, 256, 0, stream>>>(batch_p, start_p);
    start_scatter<<<BN, 256, 0, stream>>>(batch_d, start_d);
    gate_kernel<<<(NN + 127) / 128, 128, 0, stream>>>(x_p, gW1, gb1, gW2, gb2, gate_p);
    gate_kernel<<<(NN + 127) / 128, 128, 0, stream>>>(x_d, gW1, gb1, gW2, gb2, gate_d);

    // -------- side p: 3 GCN layers
    node_gemm<FIN, false><<<BN, 256, 0, stream>>>(x_p, Wp0, bufC);
    gather_kernel<<<BNV, 256, 0, stream>>>(bufC, dinv_p, bp0, rowptr_p, eSrc_p, eNorm_p, bufA);
    node_gemm<HH, true><<<BN, 256, 0, stream>>>(bufA, Wp1, bufC);
    gather_kernel<<<BNV, 256, 0, stream>>>(bufC, dinv_p, bp1, rowptr_p, eSrc_p, eNorm_p, bufB);
    node_gemm<HH, true><<<BN, 256, 0, stream>>>(bufB, Wp2, bufC);
    gather_kernel<<<BNV, 256, 0, stream>>>(bufC, dinv_p, bp2, rowptr_p, eSrc_p, eNorm_p, bufA);
    pool_kernel<<<NG, 256, 0, stream>>>(gate_p, x_p, bufA, start_p, attP, meanP);

    // -------- side d: 3 GCN layers
    node_gemm<FIN, false><<<BN, 256, 0, stream>>>(x_d, Wd0, bufC);
    gather_kernel<<<BNV, 256, 0, stream>>>(bufC, dinv_d, bd0, rowptr_d, eSrc_d, eNorm_d, bufA);
    node_gemm<HH, true><<<BN, 256, 0, stream>>>(bufA, Wd1, bufC);
    gather_kernel<<<BNV, 256, 0, stream>>>(bufC, dinv_d, bd1, rowptr_d, eSrc_d, eNorm_d, bufB);
    node_gemm<HH, true><<<BN, 256, 0, stream>>>(bufB, Wd2, bufC);
    gather_kernel<<<BNV, 256, 0, stream>>>(bufC, dinv_d, bd2, rowptr_d, eSrc_d, eNorm_d, bufA);
    pool_kernel<<<NG, 256, 0, stream>>>(gate_d, x_d, bufA, start_d, attD, meanD);

    // -------- final MLP
    final_mlp<<<NG, 128, 0, stream>>>(meanP, meanD, attP, attD,
                                      lW0, lb0, lW1, lb1, (float*)d_out);
}

// Round 5
// 1002.214 us; speedup vs baseline: 6.7257x; 1.1274x over previous
//
#include <hip/hip_runtime.h>

#define NN 50000      // nodes per side
#define NE 800000     // edges per side
#define FIN 64        // input features
#define HH 96         // hidden size
#define NG 256        // graphs per batch
#define NB ((NN + 255) / 256)   // scan blocks

// ---------------------------------------------------------------- reductions
__device__ __forceinline__ float wave_sum(float v) {
    #pragma unroll
    for (int off = 32; off > 0; off >>= 1) v += __shfl_down(v, off, 64);
    return v;
}
__device__ __forceinline__ float wave_max(float v) {
    #pragma unroll
    for (int off = 32; off > 0; off >>= 1) v = fmaxf(v, __shfl_down(v, off, 64));
    return v;
}

// ---------------------------------------------------------------- degree count (int)
__global__ __launch_bounds__(256) void count_kernel(const int* __restrict__ dst,
                                                    int* __restrict__ cnt) {
    int e = blockIdx.x * 256 + threadIdx.x;
    if (e < NE) atomicAdd(&cnt[dst[e]], 1);
}

__global__ __launch_bounds__(256) void dinv_kernel(const int* __restrict__ cnt,
                                                   float* __restrict__ dinv) {
    int n = blockIdx.x * 256 + threadIdx.x;
    if (n < NN) dinv[n] = rsqrtf((float)cnt[n] + 1.0f);
}

// ---------------------------------------------------------------- exclusive scan (3 kernels)
__global__ __launch_bounds__(256) void scan1(const int* __restrict__ cnt,
                                             int* __restrict__ blocksum) {
    __shared__ int s[256];
    int t = threadIdx.x, i = blockIdx.x * 256 + t;
    s[t] = (i < NN) ? cnt[i] : 0;
    __syncthreads();
    for (int off = 128; off > 0; off >>= 1) {
        if (t < off) s[t] += s[t + off];
        __syncthreads();
    }
    if (t == 0) blocksum[blockIdx.x] = s[0];
}

__global__ __launch_bounds__(256) void scan2(int* __restrict__ blocksum,
                                             int* __restrict__ blockoff) {
    if (threadIdx.x == 0) {
        int acc = 0;
        for (int b = 0; b < NB; ++b) { blockoff[b] = acc; acc += blocksum[b]; }
    }
}

__global__ __launch_bounds__(256) void scan3(const int* __restrict__ cnt,
                                             const int* __restrict__ blockoff,
                                             int* __restrict__ rowptr,
                                             int* __restrict__ cursor) {
    __shared__ int s[256];
    int t = threadIdx.x, i = blockIdx.x * 256 + t;
    int c = (i < NN) ? cnt[i] : 0;
    s[t] = c;
    __syncthreads();
    for (int off = 1; off < 256; off <<= 1) {
        int v = (t >= off) ? s[t - off] : 0;
        __syncthreads();
        s[t] += v;
        __syncthreads();
    }
    int excl = s[t] - c + blockoff[blockIdx.x];
    if (i < NN) { rowptr[i] = excl; cursor[i] = excl; }
    if (i == NN - 1) rowptr[NN] = excl + c;   // == NE
}

// ---------------------------------------------------------------- edge permute into CSR
__global__ __launch_bounds__(256) void permute_kernel(const int* __restrict__ src,
                                                      const int* __restrict__ dst,
                                                      const float* __restrict__ dinv,
                                                      int* __restrict__ cursor,
                                                      int* __restrict__ eSrc,
                                                      float* __restrict__ eNorm) {
    int e = blockIdx.x * 256 + threadIdx.x;
    if (e >= NE) return;
    int s = src[e], d = dst[e];
    int pos = atomicAdd(&cursor[d], 1);
    eSrc[pos] = s;
    eNorm[pos] = dinv[s] * dinv[d];
}

// ---------------------------------------------------------------- graph offsets (batch sorted)
__global__ __launch_bounds__(256) void start_init(int* __restrict__ start) {
    int g = blockIdx.x * 256 + threadIdx.x;
    if (g <= NG) start[g] = NN;
}

__global__ __launch_bounds__(256) void start_scatter(const int* __restrict__ batch,
                                                     int* __restrict__ start) {
    int i = blockIdx.x * 256 + threadIdx.x;
    if (i >= NN) return;
    int b = batch[i];
    int prev = (i == 0) ? -1 : batch[i - 1];
    for (int g = prev + 1; g <= b; ++g) start[g] = i;
}

// ---------------------------------------------------------------- gate MLP (x@gW1 relu @gW2)
__global__ __launch_bounds__(128) void gate_kernel(const float* __restrict__ x,
                                                   const float* __restrict__ gW1,
                                                   const float* __restrict__ gb1,
                                                   const float* __restrict__ gW2,
                                                   const float* __restrict__ gb2,
                                                   float* __restrict__ gate) {
    __shared__ float w1[64 * 64];
    __shared__ float xs[128 * 65];
    __shared__ float b1[64], w2[64];
    int t = threadIdx.x;
    int base = blockIdx.x * 128;
    for (int idx = t; idx < 64 * 64; idx += 128) w1[idx] = gW1[idx];
    if (t < 64) { b1[t] = gb1[t]; w2[t] = gW2[t]; }
    for (int idx = t; idx < 128 * 64; idx += 128) {
        int n = idx >> 6, k = idx & 63;
        int gn = base + n;
        xs[n * 65 + k] = (gn < NN) ? x[(size_t)gn * 64 + k] : 0.0f;
    }
    __syncthreads();

    float hid[64];
    #pragma unroll
    for (int j = 0; j < 64; ++j) hid[j] = b1[j];
    for (int k = 0; k < 64; ++k) {
        float xv = xs[t * 65 + k];
        #pragma unroll
        for (int j = 0; j < 64; ++j) hid[j] += xv * w1[k * 64 + j];
    }
    float acc = gb2[0];
    #pragma unroll
    for (int j = 0; j < 64; ++j) acc += fmaxf(hid[j], 0.0f) * w2[j];
    int n = base + t;
    if (n < NN) gate[n] = acc;
}

// ---------------------------------------------------------------- node GEMM: out = (relu?)x @ W
// grid (nodeBlocks, 4): blockIdx.y selects a 24-column group.
template <int K, bool RELU>
__global__ __launch_bounds__(256) void node_gemm(const float* __restrict__ x,
                                                 const float* __restrict__ W,
                                                 float* __restrict__ out) {
    int n = blockIdx.x * 256 + threadIdx.x;
    if (n >= NN) return;
    int c0 = blockIdx.y * 24;
    float xr[K];
    #pragma unroll
    for (int k4 = 0; k4 < K; k4 += 4) {
        float4 v = *reinterpret_cast<const float4*>(x + (size_t)n * K + k4);
        if (RELU) {
            v.x = fmaxf(v.x, 0.0f); v.y = fmaxf(v.y, 0.0f);
            v.z = fmaxf(v.z, 0.0f); v.w = fmaxf(v.w, 0.0f);
        }
        xr[k4] = v.x; xr[k4 + 1] = v.y; xr[k4 + 2] = v.z; xr[k4 + 3] = v.w;
    }
    #pragma unroll
    for (int c = c0; c < c0 + 24; c += 4) {
        float a0 = 0.f, a1 = 0.f, a2 = 0.f, a3 = 0.f;
        #pragma unroll
        for (int k = 0; k < K; ++k) {
            float4 w = *reinterpret_cast<const float4*>(W + k * HH + c);  // uniform
            a0 += xr[k] * w.x; a1 += xr[k] * w.y;
            a2 += xr[k] * w.z; a3 += xr[k] * w.w;
        }
        float4 r; r.x = a0; r.y = a1; r.z = a2; r.w = a3;
        *reinterpret_cast<float4*>(out + (size_t)n * HH + c) = r;
    }
}

// ---------------------------------------------------------------- CSR gather
__global__ __launch_bounds__(256) void gather_kernel(const float* __restrict__ xw,
                                                     const float* __restrict__ dinv,
                                                     const float* __restrict__ bias,
                                                     const int* __restrict__ rowptr,
                                                     const int* __restrict__ eSrc,
                                                     const float* __restrict__ eNorm,
                                                     float* __restrict__ out) {
    int i = blockIdx.x * 256 + threadIdx.x;   // over NN*24 float4s
    if (i >= NN * 24) return;
    int n = i / 24, q = i % 24;
    float d = dinv[n];
    float d2 = d * d;
    float4 v = reinterpret_cast<const float4*>(xw)[i];
    float4 b = reinterpret_cast<const float4*>(bias)[q];
    float ax = d2 * v.x + b.x, ay = d2 * v.y + b.y;
    float az = d2 * v.z + b.z, aw = d2 * v.w + b.w;
    int r0 = rowptr[n], r1 = rowptr[n + 1];
    for (int r = r0; r < r1; ++r) {
        int s = eSrc[r];
        float nr = eNorm[r];
        float4 u = reinterpret_cast<const float4*>(xw)[s * 24 + q];
        ax += nr * u.x; ay += nr * u.y;
        az += nr * u.z; aw += nr * u.w;
    }
    float4 r; r.x = ax; r.y = ay; r.z = az; r.w = aw;
    reinterpret_cast<float4*>(out)[i] = r;
}

// ---------------------------------------------------------------- pooling: per-graph max + denom
__global__ __launch_bounds__(256) void pool_ab(const float* __restrict__ gate,
                                               const int* __restrict__ start,
                                               float* __restrict__ mOut,
                                               float* __restrict__ denOut) {
    int g = blockIdx.x;
    int s = start[g], e = start[g + 1];
    int t = threadIdx.x;
    __shared__ float red[4];
    __shared__ float s_m;

    float lm = -3.0e38f;
    for (int i = s + t; i < e; i += 256) lm = fmaxf(lm, gate[i]);
    lm = wave_max(lm);
    if ((t & 63) == 0) red[t >> 6] = lm;
    __syncthreads();
    if (t == 0) s_m = fmaxf(fmaxf(red[0], red[1]), fmaxf(red[2], red[3]));
    __syncthreads();
    float m = s_m;

    float ls = 0.0f;
    for (int i = s + t; i < e; i += 256) ls += expf(gate[i] - m);
    ls = wave_sum(ls);
    __syncthreads();
    if ((t & 63) == 0) red[t >> 6] = ls;
    __syncthreads();
    if (t == 0) {
        mOut[g] = m;
        denOut[g] = red[0] + red[1] + red[2] + red[3];
    }
}

// per-node unnormalized weight e_i = exp(gate - m[g])
__global__ __launch_bounds__(256) void weight_kernel(const float* __restrict__ gate,
                                                     const int* __restrict__ batch,
                                                     const float* __restrict__ m,
                                                     float* __restrict__ w) {
    int i = blockIdx.x * 256 + threadIdx.x;
    if (i < NN) w[i] = expf(gate[i] - m[batch[i]]);
}

// node-parallel weighted sum of x (64 feats): attRaw[g][f] += e_i * x[i][f]
__global__ __launch_bounds__(256) void pool_att(const float* __restrict__ w,
                                                const float* __restrict__ x,
                                                const int* __restrict__ batch,
                                                float* __restrict__ attRaw) {
    int base = blockIdx.x * 64;
    int t = threadIdx.x;
    int f = t & 63, sub = t >> 6;          // 4 node subgroups
    float acc = 0.0f;
    int cur = -1;
    for (int j = 0; j < 16; ++j) {
        int i = base + sub + j * 4;        // monotone in j
        if (i >= NN) break;
        int g = batch[i];
        if (g != cur) {
            if (cur >= 0) atomicAdd(&attRaw[cur * FIN + f], acc);
            cur = g; acc = 0.0f;
        }
        acc += w[i] * x[(size_t)i * FIN + f];
    }
    if (cur >= 0) atomicAdd(&attRaw[cur * FIN + f], acc);
}

// node-parallel sum of h (96 feats, float4): meanRaw[g][:] += h[i][:]
__global__ __launch_bounds__(256) void pool_mean(const float* __restrict__ h,
                                                 const int* __restrict__ batch,
                                                 float* __restrict__ meanRaw) {
    int t = threadIdx.x;
    if (t >= 240) return;
    int q = t % 24, sub = t / 24;          // 10 node subgroups
    int base = blockIdx.x * 80;
    float4 acc = {0.f, 0.f, 0.f, 0.f};
    int cur = -1;
    for (int j = 0; j < 8; ++j) {
        int i = base + sub + j * 10;       // monotone in j
        if (i >= NN) continue;
        int g = batch[i];
        if (g != cur) {
            if (cur >= 0) {
                float* o = meanRaw + cur * HH + q * 4;
                atomicAdd(o + 0, acc.x); atomicAdd(o + 1, acc.y);
                atomicAdd(o + 2, acc.z); atomicAdd(o + 3, acc.w);
            }
            cur = g; acc.x = acc.y = acc.z = acc.w = 0.f;
        }
        float4 v = reinterpret_cast<const float4*>(h)[(size_t)i * 24 + q];
        acc.x += v.x; acc.y += v.y; acc.z += v.z; acc.w += v.w;
    }
    if (cur >= 0) {
        float* o = meanRaw + cur * HH + q * 4;
        atomicAdd(o + 0, acc.x); atomicAdd(o + 1, acc.y);
        atomicAdd(o + 2, acc.z); atomicAdd(o + 3, acc.w);
    }
}

// ---------------------------------------------------------------- final MLP (+ pooled normalization)
__global__ __launch_bounds__(128) void final_mlp(const float* __restrict__ meanP,
                                                 const float* __restrict__ meanD,
                                                 const float* __restrict__ attP,
                                                 const float* __restrict__ attD,
                                                 const float* __restrict__ denP,
                                                 const float* __restrict__ denD,
                                                 const int* __restrict__ startP,
                                                 const int* __restrict__ startD,
                                                 const float* __restrict__ lW0,
                                                 const float* __restrict__ lb0,
                                                 const float* __restrict__ lW1,
                                                 const float* __restrict__ lb1,
                                                 float* __restrict__ out) {
    __shared__ float in[2 * HH + 2 * FIN];   // 320
    __shared__ float red[2];
    int g = blockIdx.x, t = threadIdx.x;
    float cP = fmaxf((float)(startP[g + 1] - startP[g]), 1.0f);
    float cD = fmaxf((float)(startD[g + 1] - startD[g]), 1.0f);
    float dP = denP[g], dD = denD[g];
    for (int idx = t; idx < 320; idx += 128) {
        float v;
        if (idx < 96)       v = meanP[g * HH + idx] / cP;
        else if (idx < 192) v = meanD[g * HH + idx - 96] / cD;
        else if (idx < 256) v = (dP > 0.f) ? attP[g * FIN + idx - 192] / dP : 0.0f;
        else                v = (dD > 0.f) ? attD[g * FIN + idx - 256] / dD : 0.0f;
        in[idx] = v;
    }
    __syncthreads();
    float hidv = 0.0f;
    if (t < HH) {
        float acc = lb0[t];
        for (int k = 0; k < 320; ++k) acc += in[k] * lW0[k * HH + t];
        hidv = fmaxf(acc, 0.0f) * lW1[t];
    }
    float v = wave_sum(hidv);
    if ((t & 63) == 0) red[t >> 6] = v;
    __syncthreads();
    if (t == 0) out[g] = red[0] + red[1] + lb1[0];
}

// ---------------------------------------------------------------- launch
extern "C" void kernel_launch(void* const* d_in, const int* in_sizes, int n_in,
                              void* d_out, int out_size, void* d_ws, size_t ws_size,
                              hipStream_t stream) {
    const float* x_p = (const float*)d_in[0];
    const float* x_d = (const float*)d_in[1];
    const int* ei_p = (const int*)d_in[4];
    const int* ei_d = (const int*)d_in[5];
    const int* batch_p = (const int*)d_in[6];
    const int* batch_d = (const int*)d_in[7];
    const float* Wp0 = (const float*)d_in[8];  const float* bp0 = (const float*)d_in[9];
    const float* Wp1 = (const float*)d_in[10]; const float* bp1 = (const float*)d_in[11];
    const float* Wp2 = (const float*)d_in[12]; const float* bp2 = (const float*)d_in[13];
    const float* Wd0 = (const float*)d_in[14]; const float* bd0 = (const float*)d_in[15];
    const float* Wd1 = (const float*)d_in[16]; const float* bd1 = (const float*)d_in[17];
    const float* Wd2 = (const float*)d_in[18]; const float* bd2 = (const float*)d_in[19];
    const float* gW1 = (const float*)d_in[20]; const float* gb1 = (const float*)d_in[21];
    const float* gW2 = (const float*)d_in[22]; const float* gb2 = (const float*)d_in[23];
    const float* lW0 = (const float*)d_in[24]; const float* lb0 = (const float*)d_in[25];
    const float* lW1 = (const float*)d_in[26]; const float* lb1 = (const float*)d_in[27];

    const int* src_p = ei_p;        const int* dst_p = ei_p + NE;
    const int* src_d = ei_d;        const int* dst_d = ei_d + NE;

    // -------- workspace carve-up
    char* ws = (char*)d_ws;
    size_t off = 0;
    auto alloc = [&](size_t bytes) -> void* {
        void* p = ws + off;
        off = (off + bytes + 255) & ~(size_t)255;
        return p;
    };
    float* bufA = (float*)alloc((size_t)NN * HH * 4);
    float* bufB = (float*)alloc((size_t)NN * HH * 4);
    float* bufC = (float*)alloc((size_t)NN * HH * 4);   // xw scratch
    int* cnt_p = (int*)alloc(NN * 4);
    int* cnt_d = (int*)alloc(NN * 4);
    float* dinv_p = (float*)alloc(NN * 4);
    float* dinv_d = (float*)alloc(NN * 4);
    int* rowptr_p = (int*)alloc((NN + 1) * 4);
    int* rowptr_d = (int*)alloc((NN + 1) * 4);
    int* cursor_p = (int*)alloc(NN * 4);
    int* cursor_d = (int*)alloc(NN * 4);
    int* eSrc_p = (int*)alloc((size_t)NE * 4);
    int* eSrc_d = (int*)alloc((size_t)NE * 4);
    float* eNorm_p = (float*)alloc((size_t)NE * 4);
    float* eNorm_d = (float*)alloc((size_t)NE * 4);
    int* blocksum = (int*)alloc(NB * 4);
    int* blockoff = (int*)alloc(NB * 4);
    float* gate_p = (float*)alloc(NN * 4);
    float* gate_d = (float*)alloc(NN * 4);
    float* wgt_p = (float*)alloc(NN * 4);
    float* wgt_d = (float*)alloc(NN * 4);
    int* start_p = (int*)alloc((NG + 1) * 4);
    int* start_d = (int*)alloc((NG + 1) * 4);
    float* m_p = (float*)alloc(NG * 4);
    float* m_d = (float*)alloc(NG * 4);
    float* den_p = (float*)alloc(NG * 4);
    float* den_d = (float*)alloc(NG * 4);
    // pooled raw accumulators — contiguous for one memset
    float* pooled = (float*)alloc((size_t)NG * (2 * HH + 2 * FIN) * 4);
    float* meanP = pooled;                       // NG*HH
    float* meanD = meanP + (size_t)NG * HH;      // NG*HH
    float* attP  = meanD + (size_t)NG * HH;      // NG*FIN
    float* attD  = attP + (size_t)NG * FIN;      // NG*FIN
    (void)ws_size; (void)n_in; (void)in_sizes; (void)out_size;

    const int BE = (NE + 255) / 256;
    const int BN = NB;
    const int BNV = (NN * 24 + 255) / 256;
    const dim3 GEMM_GRID(NB, 4);
    const int BATT = (NN + 63) / 64;
    const int BMEAN = (NN + 79) / 80;

    // -------- CSR build + offsets + gate + pooled init
    hipMemsetAsync(cnt_p, 0, NN * 4, stream);
    hipMemsetAsync(cnt_d, 0, NN * 4, stream);
    hipMemsetAsync(pooled, 0, (size_t)NG * (2 * HH + 2 * FIN) * 4, stream);
    count_kernel<<<BE, 256, 0, stream>>>(dst_p, cnt_p);
    count_kernel<<<BE, 256, 0, stream>>>(dst_d, cnt_d);
    dinv_kernel<<<BN, 256, 0, stream>>>(cnt_p, dinv_p);
    dinv_kernel<<<BN, 256, 0, stream>>>(cnt_d, dinv_d);
    scan1<<<NB, 256, 0, stream>>>(cnt_p, blocksum);
    scan2<<<1, 256, 0, stream>>>(blocksum, blockoff);
    scan3<<<NB, 256, 0, stream>>>(cnt_p, blockoff, rowptr_p, cursor_p);
    scan1<<<NB, 256, 0, stream>>>(cnt_d, blocksum);
    scan2<<<1, 256, 0, stream>>>(blocksum, blockoff);
    scan3<<<NB, 256, 0, stream>>>(cnt_d, blockoff, rowptr_d, cursor_d);
    permute_kernel<<<BE, 256, 0, stream>>>(src_p, dst_p, dinv_p, cursor_p, eSrc_p, eNorm_p);
    permute_kernel<<<BE, 256, 0, stream>>>(src_d, dst_d, dinv_d, cursor_d, eSrc_d, eNorm_d);
    start_init<<<2, 256, 0, stream>>>(start_p);
    start_init<<<2, 256, 0, stream>>>(start_d);
    start_scatter<<<BN, 256, 0, stream>>>(batch_p, start_p);
    start_scatter<<<BN, 256, 0, stream>>>(batch_d, start_d);
    gate_kernel<<<(NN + 127) / 128, 128, 0, stream>>>(x_p, gW1, gb1, gW2, gb2, gate_p);
    gate_kernel<<<(NN + 127) / 128, 128, 0, stream>>>(x_d, gW1, gb1, gW2, gb2, gate_d);

    // -------- attention pooling (raw features)
    pool_ab<<<NG, 256, 0, stream>>>(gate_p, start_p, m_p, den_p);
    pool_ab<<<NG, 256, 0, stream>>>(gate_d, start_d, m_d, den_d);
    weight_kernel<<<BN, 256, 0, stream>>>(gate_p, batch_p, m_p, wgt_p);
    weight_kernel<<<BN, 256, 0, stream>>>(gate_d, batch_d, m_d, wgt_d);
    pool_att<<<BATT, 256, 0, stream>>>(wgt_p, x_p, batch_p, attP);
    pool_att<<<BATT, 256, 0, stream>>>(wgt_d, x_d, batch_d, attD);

    // -------- side p: 3 GCN layers
    node_gemm<FIN, false><<<GEMM_GRID, 256, 0, stream>>>(x_p, Wp0, bufC);
    gather_kernel<<<BNV, 256, 0, stream>>>(bufC, dinv_p, bp0, rowptr_p, eSrc_p, eNorm_p, bufA);
    node_gemm<HH, true><<<GEMM_GRID, 256, 0, stream>>>(bufA, Wp1, bufC);
    gather_kernel<<<BNV, 256, 0, stream>>>(bufC, dinv_p, bp1, rowptr_p, eSrc_p, eNorm_p, bufB);
    node_gemm<HH, true><<<GEMM_GRID, 256, 0, stream>>>(bufB, Wp2, bufC);
    gather_kernel<<<BNV, 256, 0, stream>>>(bufC, dinv_p, bp2, rowptr_p, eSrc_p, eNorm_p, bufA);
    pool_mean<<<BMEAN, 256, 0, stream>>>(bufA, batch_p, meanP);

    // -------- side d: 3 GCN layers
    node_gemm<FIN, false><<<GEMM_GRID, 256, 0, stream>>>(x_d, Wd0, bufC);
    gather_kernel<<<BNV, 256, 0, stream>>>(bufC, dinv_d, bd0, rowptr_d, eSrc_d, eNorm_d, bufA);
    node_gemm<HH, true><<<GEMM_GRID, 256, 0, stream>>>(bufA, Wd1, bufC);
    gather_kernel<<<BNV, 256, 0, stream>>>(bufC, dinv_d, bd1, rowptr_d, eSrc_d, eNorm_d, bufB);
    node_gemm<HH, true><<<GEMM_GRID, 256, 0, stream>>>(bufB, Wd2, bufC);
    gather_kernel<<<BNV, 256, 0, stream>>>(bufC, dinv_d, bd2, rowptr_d, eSrc_d, eNorm_d, bufA);
    pool_mean<<<BMEAN, 256, 0, stream>>>(bufA, batch_d, meanD);

    // -------- final MLP
    final_mlp<<<NG, 128, 0, stream>>>(meanP, meanD, attP, attD,
                                      den_p, den_d, start_p, start_d,
                                      lW0, lb0, lW1, lb1, (float*)d_out);
}

// Round 6
// 817.298 us; speedup vs baseline: 8.2474x; 1.2263x over previous
//
#include <hip/hip_runtime.h>

#define NN 50000      // nodes per side
#define NE 800000     // edges per side
#define FIN 64        // input features
#define HH 96         // hidden size
#define NG 256        // graphs per batch
#define NB ((NN + 255) / 256)   // node blocks

// ---------------------------------------------------------------- helpers
__device__ __forceinline__ float wave_sum(float v) {
    #pragma unroll
    for (int off = 32; off > 0; off >>= 1) v += __shfl_down(v, off, 64);
    return v;
}
__device__ __forceinline__ float wave_max(float v) {
    #pragma unroll
    for (int off = 32; off > 0; off >>= 1) v = fmaxf(v, __shfl_down(v, off, 64));
    return v;
}
__device__ __forceinline__ float bf2f(unsigned short b) {
    return __uint_as_float(((unsigned int)b) << 16);
}
__device__ __forceinline__ unsigned short f2bf(float f) {
    unsigned int u = __float_as_uint(f);
    u += 0x7FFFu + ((u >> 16) & 1u);          // round-to-nearest-even
    return (unsigned short)(u >> 16);
}

// ---------------------------------------------------------------- degree count (both sides)
__global__ __launch_bounds__(256) void count_both(const int* __restrict__ dstP,
                                                  const int* __restrict__ dstD,
                                                  int* __restrict__ cnt2) {
    int e = blockIdx.x * 256 + threadIdx.x;
    const int* dst = blockIdx.y ? dstD : dstP;
    int* cnt = cnt2 + blockIdx.y * NN;
    if (e < NE) atomicAdd(&cnt[dst[e]], 1);
}

// ---------------------------------------------------------------- exclusive scan (3 kernels, both sides)
__global__ __launch_bounds__(256) void scan1_both(const int* __restrict__ cnt2,
                                                  int* __restrict__ blocksum2) {
    __shared__ int s[256];
    int side = blockIdx.y;
    int t = threadIdx.x, i = blockIdx.x * 256 + t;
    const int* cnt = cnt2 + side * NN;
    s[t] = (i < NN) ? cnt[i] : 0;
    __syncthreads();
    for (int off = 128; off > 0; off >>= 1) {
        if (t < off) s[t] += s[t + off];
        __syncthreads();
    }
    if (t == 0) blocksum2[side * NB + blockIdx.x] = s[0];
}

__global__ __launch_bounds__(256) void scan2_both(const int* __restrict__ blocksum2,
                                                  int* __restrict__ blockoff2) {
    int side = blockIdx.x;
    if (threadIdx.x == 0) {
        int acc = 0;
        const int* bs = blocksum2 + side * NB;
        int* bo = blockoff2 + side * NB;
        for (int b = 0; b < NB; ++b) { bo[b] = acc; acc += bs[b]; }
    }
}

// also emits dinv = rsqrt(cnt+1)
__global__ __launch_bounds__(256) void scan3_both(const int* __restrict__ cnt2,
                                                  const int* __restrict__ blockoff2,
                                                  int* __restrict__ rowptr2,
                                                  int* __restrict__ cursor2,
                                                  float* __restrict__ dinv2) {
    __shared__ int s[256];
    int side = blockIdx.y;
    int t = threadIdx.x, i = blockIdx.x * 256 + t;
    const int* cnt = cnt2 + side * NN;
    int* rowptr = rowptr2 + side * (NN + 1);
    int* cursor = cursor2 + side * NN;
    float* dinv = dinv2 + side * NN;
    int c = (i < NN) ? cnt[i] : 0;
    s[t] = c;
    __syncthreads();
    for (int off = 1; off < 256; off <<= 1) {
        int v = (t >= off) ? s[t - off] : 0;
        __syncthreads();
        s[t] += v;
        __syncthreads();
    }
    int excl = s[t] - c + blockoff2[side * NB + blockIdx.x];
    if (i < NN) {
        rowptr[i] = excl;
        cursor[i] = excl;
        dinv[i] = rsqrtf((float)c + 1.0f);
    }
    if (i == NN - 1) rowptr[NN] = excl + c;   // == NE
}

// ---------------------------------------------------------------- edge permute (eSrc only)
__global__ __launch_bounds__(256) void permute_both(const int* __restrict__ srcP,
                                                    const int* __restrict__ dstP,
                                                    const int* __restrict__ srcD,
                                                    const int* __restrict__ dstD,
                                                    int* __restrict__ cursor2,
                                                    int* __restrict__ eSrcP,
                                                    int* __restrict__ eSrcD) {
    int e = blockIdx.x * 256 + threadIdx.x;
    if (e >= NE) return;
    int side = blockIdx.y;
    const int* src = side ? srcD : srcP;
    const int* dst = side ? dstD : dstP;
    int* cursor = cursor2 + side * NN;
    int* eS = side ? eSrcD : eSrcP;
    int s = src[e], d = dst[e];
    int pos = atomicAdd(&cursor[d], 1);
    eS[pos] = s;
}

// ---------------------------------------------------------------- graph offsets (batch sorted; init fused)
__global__ __launch_bounds__(256) void start_both(const int* __restrict__ batchP,
                                                  const int* __restrict__ batchD,
                                                  int* __restrict__ start2) {
    int i = blockIdx.x * 256 + threadIdx.x;
    if (i >= NN) return;
    int side = blockIdx.y;
    const int* batch = side ? batchD : batchP;
    int* start = start2 + side * (NG + 1);
    int b = batch[i];
    int prev = (i == 0) ? -1 : batch[i - 1];
    for (int g = prev + 1; g <= b; ++g) start[g] = i;
    if (i == NN - 1) {
        for (int g = b + 1; g <= NG; ++g) start[g] = NN;
    }
}

// ---------------------------------------------------------------- gate MLP (both sides)
__global__ __launch_bounds__(128) void gate_both(const float* __restrict__ xP,
                                                 const float* __restrict__ xD,
                                                 const float* __restrict__ gW1,
                                                 const float* __restrict__ gb1,
                                                 const float* __restrict__ gW2,
                                                 const float* __restrict__ gb2,
                                                 float* __restrict__ gate2) {
    __shared__ float w1[64 * 64];
    __shared__ float xs[128 * 65];
    __shared__ float b1[64], w2[64];
    int side = blockIdx.y;
    const float* x = side ? xD : xP;
    float* gate = gate2 + side * NN;
    int t = threadIdx.x;
    int base = blockIdx.x * 128;
    for (int idx = t; idx < 64 * 64; idx += 128) w1[idx] = gW1[idx];
    if (t < 64) { b1[t] = gb1[t]; w2[t] = gW2[t]; }
    for (int idx = t; idx < 128 * 64; idx += 128) {
        int n = idx >> 6, k = idx & 63;
        int gn = base + n;
        xs[n * 65 + k] = (gn < NN) ? x[(size_t)gn * 64 + k] : 0.0f;
    }
    __syncthreads();

    float hid[64];
    #pragma unroll
    for (int j = 0; j < 64; ++j) hid[j] = b1[j];
    for (int k = 0; k < 64; ++k) {
        float xv = xs[t * 65 + k];
        #pragma unroll
        for (int j = 0; j < 64; ++j) hid[j] += xv * w1[k * 64 + j];
    }
    float acc = gb2[0];
    #pragma unroll
    for (int j = 0; j < 64; ++j) acc += fmaxf(hid[j], 0.0f) * w2[j];
    int n = base + t;
    if (n < NN) gate[n] = acc;
}

// ---------------------------------------------------------------- node GEMM: xw(bf16) = (relu?)in @ W
// grid (NB, 4, 2): blockIdx.y = 24-column group, blockIdx.z = side.
template <int K, bool RELU>
__global__ __launch_bounds__(256) void gemm_both(const float* __restrict__ inP,
                                                 const float* __restrict__ inD,
                                                 const float* __restrict__ WP,
                                                 const float* __restrict__ WD,
                                                 ushort4* __restrict__ xwP,
                                                 ushort4* __restrict__ xwD) {
    int n = blockIdx.x * 256 + threadIdx.x;
    if (n >= NN) return;
    int side = blockIdx.z;
    const float* x = side ? inD : inP;
    const float* W = side ? WD : WP;
    ushort4* xw = side ? xwD : xwP;
    int c0 = blockIdx.y * 24;
    float xr[K];
    #pragma unroll
    for (int k4 = 0; k4 < K; k4 += 4) {
        float4 v = *reinterpret_cast<const float4*>(x + (size_t)n * K + k4);
        if (RELU) {
            v.x = fmaxf(v.x, 0.0f); v.y = fmaxf(v.y, 0.0f);
            v.z = fmaxf(v.z, 0.0f); v.w = fmaxf(v.w, 0.0f);
        }
        xr[k4] = v.x; xr[k4 + 1] = v.y; xr[k4 + 2] = v.z; xr[k4 + 3] = v.w;
    }
    #pragma unroll
    for (int c = c0; c < c0 + 24; c += 4) {
        float a0 = 0.f, a1 = 0.f, a2 = 0.f, a3 = 0.f;
        #pragma unroll
        for (int k = 0; k < K; ++k) {
            float4 w = *reinterpret_cast<const float4*>(W + k * HH + c);  // uniform
            a0 += xr[k] * w.x; a1 += xr[k] * w.y;
            a2 += xr[k] * w.z; a3 += xr[k] * w.w;
        }
        ushort4 o;
        o.x = f2bf(a0); o.y = f2bf(a1); o.z = f2bf(a2); o.w = f2bf(a3);
        xw[n * 24 + (c >> 2)] = o;
    }
}

// ---------------------------------------------------------------- CSR gather (bf16 xw, norm from dinv)
// agg[n] = dinv[n]^2*xw[n] + dinv[n]*sum(dinv[s]*xw[s]) + bias
__global__ __launch_bounds__(256) void gather_both(const ushort4* __restrict__ xwP,
                                                   const ushort4* __restrict__ xwD,
                                                   const float* __restrict__ dinv2,
                                                   const float* __restrict__ biasP,
                                                   const float* __restrict__ biasD,
                                                   const int* __restrict__ rowptr2,
                                                   const int* __restrict__ eSrcP,
                                                   const int* __restrict__ eSrcD,
                                                   float* __restrict__ aggP,
                                                   float* __restrict__ aggD) {
    int i = blockIdx.x * 256 + threadIdx.x;   // over NN*24 4-feature chunks
    if (i >= NN * 24) return;
    int side = blockIdx.y;
    const ushort4* xw = side ? xwD : xwP;
    const float* dv = dinv2 + side * NN;
    const float* bias = side ? biasD : biasP;
    const int* rp = rowptr2 + side * (NN + 1);
    const int* es = side ? eSrcD : eSrcP;
    float* agg = side ? aggD : aggP;

    int n = i / 24, q = i - n * 24;
    int r0 = rp[n], r1 = rp[n + 1];
    float ex = 0.f, ey = 0.f, ez = 0.f, ew = 0.f;
    int r = r0;
    for (; r + 2 <= r1; r += 2) {              // unroll-2: two independent chains
        int s0 = es[r], s1 = es[r + 1];
        float w0 = dv[s0], w1 = dv[s1];
        ushort4 u0 = xw[s0 * 24 + q];
        ushort4 u1 = xw[s1 * 24 + q];
        ex += w0 * bf2f(u0.x) + w1 * bf2f(u1.x);
        ey += w0 * bf2f(u0.y) + w1 * bf2f(u1.y);
        ez += w0 * bf2f(u0.z) + w1 * bf2f(u1.z);
        ew += w0 * bf2f(u0.w) + w1 * bf2f(u1.w);
    }
    if (r < r1) {
        int s0 = es[r];
        float w0 = dv[s0];
        ushort4 u0 = xw[s0 * 24 + q];
        ex += w0 * bf2f(u0.x); ey += w0 * bf2f(u0.y);
        ez += w0 * bf2f(u0.z); ew += w0 * bf2f(u0.w);
    }
    float d = dv[n], d2 = d * d;
    ushort4 su = xw[i];
    float4 b = reinterpret_cast<const float4*>(bias)[q];
    float4 o;
    o.x = d2 * bf2f(su.x) + d * ex + b.x;
    o.y = d2 * bf2f(su.y) + d * ey + b.y;
    o.z = d2 * bf2f(su.z) + d * ez + b.z;
    o.w = d2 * bf2f(su.w) + d * ew + b.w;
    reinterpret_cast<float4*>(agg)[i] = o;
}

// ---------------------------------------------------------------- per-graph max + denom + weights
__global__ __launch_bounds__(256) void pool_ab_wgt(const float* __restrict__ gate2,
                                                   const int* __restrict__ start2,
                                                   float* __restrict__ den2,
                                                   float* __restrict__ wgt2) {
    int side = blockIdx.y, g = blockIdx.x, t = threadIdx.x;
    const float* gate = gate2 + side * NN;
    const int* start = start2 + side * (NG + 1);
    float* den = den2 + side * NG;
    float* wgt = wgt2 + side * NN;
    int s = start[g], e = start[g + 1];
    __shared__ float red[4];
    __shared__ float s_m;

    float lm = -3.0e38f;
    for (int i = s + t; i < e; i += 256) lm = fmaxf(lm, gate[i]);
    lm = wave_max(lm);
    if ((t & 63) == 0) red[t >> 6] = lm;
    __syncthreads();
    if (t == 0) s_m = fmaxf(fmaxf(red[0], red[1]), fmaxf(red[2], red[3]));
    __syncthreads();
    float m = s_m;

    float ls = 0.0f;
    for (int i = s + t; i < e; i += 256) {
        float w = expf(gate[i] - m);
        wgt[i] = w;
        ls += w;
    }
    ls = wave_sum(ls);
    __syncthreads();
    if ((t & 63) == 0) red[t >> 6] = ls;
    __syncthreads();
    if (t == 0) den[g] = red[0] + red[1] + red[2] + red[3];
}

// ---------------------------------------------------------------- node-parallel att pool (raw x)
__global__ __launch_bounds__(256) void pool_att_both(const float* __restrict__ wgt2,
                                                     const float* __restrict__ xP,
                                                     const float* __restrict__ xD,
                                                     const int* __restrict__ batchP,
                                                     const int* __restrict__ batchD,
                                                     float* __restrict__ attP,
                                                     float* __restrict__ attD) {
    int side = blockIdx.y;
    const float* w = wgt2 + side * NN;
    const float* x = side ? xD : xP;
    const int* batch = side ? batchD : batchP;
    float* attRaw = side ? attD : attP;
    int base = blockIdx.x * 64;
    int t = threadIdx.x;
    int f = t & 63, sub = t >> 6;          // 4 node subgroups
    float acc = 0.0f;
    int cur = -1;
    for (int j = 0; j < 16; ++j) {
        int i = base + sub + j * 4;        // monotone in j
        if (i >= NN) break;
        int g = batch[i];
        if (g != cur) {
            if (cur >= 0) atomicAdd(&attRaw[cur * FIN + f], acc);
            cur = g; acc = 0.0f;
        }
        acc += w[i] * x[(size_t)i * FIN + f];
    }
    if (cur >= 0) atomicAdd(&attRaw[cur * FIN + f], acc);
}

// ---------------------------------------------------------------- node-parallel mean pool (h fp32)
__global__ __launch_bounds__(256) void pool_mean_both(const float* __restrict__ hP,
                                                      const float* __restrict__ hD,
                                                      const int* __restrict__ batchP,
                                                      const int* __restrict__ batchD,
                                                      float* __restrict__ meanP,
                                                      float* __restrict__ meanD) {
    int t = threadIdx.x;
    if (t >= 240) return;
    int side = blockIdx.y;
    const float* h = side ? hD : hP;
    const int* batch = side ? batchD : batchP;
    float* meanRaw = side ? meanD : meanP;
    int q = t % 24, sub = t / 24;          // 10 node subgroups
    int base = blockIdx.x * 80;
    float4 acc = {0.f, 0.f, 0.f, 0.f};
    int cur = -1;
    for (int j = 0; j < 8; ++j) {
        int i = base + sub + j * 10;       // monotone in j
        if (i >= NN) continue;
        int g = batch[i];
        if (g != cur) {
            if (cur >= 0) {
                float* o = meanRaw + cur * HH + q * 4;
                atomicAdd(o + 0, acc.x); atomicAdd(o + 1, acc.y);
                atomicAdd(o + 2, acc.z); atomicAdd(o + 3, acc.w);
            }
            cur = g; acc.x = acc.y = acc.z = acc.w = 0.f;
        }
        float4 v = reinterpret_cast<const float4*>(h)[(size_t)i * 24 + q];
        acc.x += v.x; acc.y += v.y; acc.z += v.z; acc.w += v.w;
    }
    if (cur >= 0) {
        float* o = meanRaw + cur * HH + q * 4;
        atomicAdd(o + 0, acc.x); atomicAdd(o + 1, acc.y);
        atomicAdd(o + 2, acc.z); atomicAdd(o + 3, acc.w);
    }
}

// ---------------------------------------------------------------- final MLP (+ pooled normalization)
__global__ __launch_bounds__(128) void final_mlp(const float* __restrict__ meanP,
                                                 const float* __restrict__ meanD,
                                                 const float* __restrict__ attP,
                                                 const float* __restrict__ attD,
                                                 const float* __restrict__ den2,
                                                 const int* __restrict__ start2,
                                                 const float* __restrict__ lW0,
                                                 const float* __restrict__ lb0,
                                                 const float* __restrict__ lW1,
                                                 const float* __restrict__ lb1,
                                                 float* __restrict__ out) {
    __shared__ float in[2 * HH + 2 * FIN];   // 320
    __shared__ float red[2];
    int g = blockIdx.x, t = threadIdx.x;
    const int* startP = start2;
    const int* startD = start2 + (NG + 1);
    float cP = fmaxf((float)(startP[g + 1] - startP[g]), 1.0f);
    float cD = fmaxf((float)(startD[g + 1] - startD[g]), 1.0f);
    float dP = den2[g], dD = den2[NG + g];
    for (int idx = t; idx < 320; idx += 128) {
        float v;
        if (idx < 96)       v = meanP[g * HH + idx] / cP;
        else if (idx < 192) v = meanD[g * HH + idx - 96] / cD;
        else if (idx < 256) v = (dP > 0.f) ? attP[g * FIN + idx - 192] / dP : 0.0f;
        else                v = (dD > 0.f) ? attD[g * FIN + idx - 256] / dD : 0.0f;
        in[idx] = v;
    }
    __syncthreads();
    float hidv = 0.0f;
    if (t < HH) {
        float acc = lb0[t];
        for (int k = 0; k < 320; ++k) acc += in[k] * lW0[k * HH + t];
        hidv = fmaxf(acc, 0.0f) * lW1[t];
    }
    float v = wave_sum(hidv);
    if ((t & 63) == 0) red[t >> 6] = v;
    __syncthreads();
    if (t == 0) out[g] = red[0] + red[1] + lb1[0];
}

// ---------------------------------------------------------------- launch
extern "C" void kernel_launch(void* const* d_in, const int* in_sizes, int n_in,
                              void* d_out, int out_size, void* d_ws, size_t ws_size,
                              hipStream_t stream) {
    const float* x_p = (const float*)d_in[0];
    const float* x_d = (const float*)d_in[1];
    const int* ei_p = (const int*)d_in[4];
    const int* ei_d = (const int*)d_in[5];
    const int* batch_p = (const int*)d_in[6];
    const int* batch_d = (const int*)d_in[7];
    const float* Wp0 = (const float*)d_in[8];  const float* bp0 = (const float*)d_in[9];
    const float* Wp1 = (const float*)d_in[10]; const float* bp1 = (const float*)d_in[11];
    const float* Wp2 = (const float*)d_in[12]; const float* bp2 = (const float*)d_in[13];
    const float* Wd0 = (const float*)d_in[14]; const float* bd0 = (const float*)d_in[15];
    const float* Wd1 = (const float*)d_in[16]; const float* bd1 = (const float*)d_in[17];
    const float* Wd2 = (const float*)d_in[18]; const float* bd2 = (const float*)d_in[19];
    const float* gW1 = (const float*)d_in[20]; const float* gb1 = (const float*)d_in[21];
    const float* gW2 = (const float*)d_in[22]; const float* gb2 = (const float*)d_in[23];
    const float* lW0 = (const float*)d_in[24]; const float* lb0 = (const float*)d_in[25];
    const float* lW1 = (const float*)d_in[26]; const float* lb1 = (const float*)d_in[27];

    const int* src_p = ei_p;        const int* dst_p = ei_p + NE;
    const int* src_d = ei_d;        const int* dst_d = ei_d + NE;

    // -------- workspace carve-up
    char* ws = (char*)d_ws;
    size_t off = 0;
    auto alloc = [&](size_t bytes) -> void* {
        void* p = ws + off;
        off = (off + bytes + 255) & ~(size_t)255;
        return p;
    };
    float* agg_p = (float*)alloc((size_t)NN * HH * 4);        // fp32 layer io
    float* agg_d = (float*)alloc((size_t)NN * HH * 4);
    ushort4* xw_p = (ushort4*)alloc((size_t)NN * HH * 2);     // bf16 gemm out
    ushort4* xw_d = (ushort4*)alloc((size_t)NN * HH * 2);
    int* cnt2 = (int*)alloc((size_t)2 * NN * 4);              // one memset
    float* dinv2 = (float*)alloc((size_t)2 * NN * 4);
    int* rowptr2 = (int*)alloc((size_t)2 * (NN + 1) * 4);
    int* cursor2 = (int*)alloc((size_t)2 * NN * 4);
    int* eSrc_p = (int*)alloc((size_t)NE * 4);
    int* eSrc_d = (int*)alloc((size_t)NE * 4);
    int* blocksum2 = (int*)alloc((size_t)2 * NB * 4);
    int* blockoff2 = (int*)alloc((size_t)2 * NB * 4);
    float* gate2 = (float*)alloc((size_t)2 * NN * 4);
    float* wgt2 = (float*)alloc((size_t)2 * NN * 4);
    int* start2 = (int*)alloc((size_t)2 * (NG + 1) * 4);
    float* den2 = (float*)alloc((size_t)2 * NG * 4);
    float* pooled = (float*)alloc((size_t)NG * (2 * HH + 2 * FIN) * 4);
    float* meanP = pooled;
    float* meanD = meanP + (size_t)NG * HH;
    float* attP  = meanD + (size_t)NG * HH;
    float* attD  = attP + (size_t)NG * FIN;
    (void)ws_size; (void)n_in; (void)in_sizes; (void)out_size;

    const int BE = (NE + 255) / 256;
    const int BNV = (NN * 24 + 255) / 256;
    const dim3 G2E(BE, 2), G2N(NB, 2), G2V(BNV, 2);
    const dim3 GEMM_GRID(NB, 4, 2);
    const dim3 GATE_GRID((NN + 127) / 128, 2);
    const dim3 GAB(NG, 2);
    const dim3 GATT((NN + 63) / 64, 2);
    const dim3 GMEAN((NN + 79) / 80, 2);

    // -------- CSR build + offsets + gate + pooled init
    hipMemsetAsync(cnt2, 0, (size_t)2 * NN * 4, stream);
    hipMemsetAsync(pooled, 0, (size_t)NG * (2 * HH + 2 * FIN) * 4, stream);
    count_both<<<G2E, 256, 0, stream>>>(dst_p, dst_d, cnt2);
    scan1_both<<<G2N, 256, 0, stream>>>(cnt2, blocksum2);
    scan2_both<<<2, 256, 0, stream>>>(blocksum2, blockoff2);
    scan3_both<<<G2N, 256, 0, stream>>>(cnt2, blockoff2, rowptr2, cursor2, dinv2);
    permute_both<<<G2E, 256, 0, stream>>>(src_p, dst_p, src_d, dst_d, cursor2, eSrc_p, eSrc_d);
    start_both<<<G2N, 256, 0, stream>>>(batch_p, batch_d, start2);
    gate_both<<<GATE_GRID, 128, 0, stream>>>(x_p, x_d, gW1, gb1, gW2, gb2, gate2);
    pool_ab_wgt<<<GAB, 256, 0, stream>>>(gate2, start2, den2, wgt2);
    pool_att_both<<<GATT, 256, 0, stream>>>(wgt2, x_p, x_d, batch_p, batch_d, attP, attD);

    // -------- 3 GCN layers, both sides per dispatch
    gemm_both<FIN, false><<<GEMM_GRID, 256, 0, stream>>>(x_p, x_d, Wp0, Wd0, xw_p, xw_d);
    gather_both<<<G2V, 256, 0, stream>>>(xw_p, xw_d, dinv2, bp0, bd0, rowptr2, eSrc_p, eSrc_d, agg_p, agg_d);
    gemm_both<HH, true><<<GEMM_GRID, 256, 0, stream>>>(agg_p, agg_d, Wp1, Wd1, xw_p, xw_d);
    gather_both<<<G2V, 256, 0, stream>>>(xw_p, xw_d, dinv2, bp1, bd1, rowptr2, eSrc_p, eSrc_d, agg_p, agg_d);
    gemm_both<HH, true><<<GEMM_GRID, 256, 0, stream>>>(agg_p, agg_d, Wp2, Wd2, xw_p, xw_d);
    gather_both<<<G2V, 256, 0, stream>>>(xw_p, xw_d, dinv2, bp2, bd2, rowptr2, eSrc_p, eSrc_d, agg_p, agg_d);
    pool_mean_both<<<GMEAN, 256, 0, stream>>>(agg_p, agg_d, batch_p, batch_d, meanP, meanD);

    // -------- final MLP
    final_mlp<<<NG, 128, 0, stream>>>(meanP, meanD, attP, attD, den2, start2,
                                      lW0, lb0, lW1, lb1, (float*)d_out);
}